// Round 13
// baseline (818.869 us; speedup 1.0000x reference)
//
#include <hip/hip_runtime.h>
#include <math.h>

#define NNODES 50000
#define NEDGES 1600000
#define DOUT 256
#define NEG_SLOPE 0.2f
#define SCANB ((NNODES + 255) / 256)
#define NB ((NNODES + 255) / 256)   // dst buckets of 256 nodes (196)
#define BCAP 10240                  // bucket capacity (mean ~8420, >15 sigma margin)
#define CHUNK 8192                  // edges per bucket block
#define BBUCKET ((NEDGES + NNODES + CHUNK - 1) / CHUNK)   // 202
#define BCASTX 2048
#define GEMM_GRID ((NNODES + 63) / 64)                    // 782
#define NSLICE 8                    // column slices (32 cols = 64B bf16 each)

typedef __attribute__((ext_vector_type(8))) short short8;
typedef __attribute__((ext_vector_type(8))) unsigned short u16x8;
typedef __attribute__((ext_vector_type(4))) float f32x4;

__device__ __forceinline__ float lrelu(float e) { return e > 0.f ? e : NEG_SLOPE * e; }
__device__ __forceinline__ float b2f(unsigned short u) {
  union { unsigned u; float f; } c; c.u = ((unsigned)u) << 16; return c.f;
}
__device__ __forceinline__ unsigned short f2b(float f) {
  union { float f; unsigned u; } c; c.f = f;
  return (unsigned short)((c.u + 0x7fffu + ((c.u >> 16) & 1u)) >> 16);
}

// ---------------- fat pre kernel: bucket || castX || castW1-3 ----------------
__device__ void castW_body(int bid, int DIN, const float* __restrict__ W,
                           unsigned short* __restrict__ Wt) {
  const int idx = bid * 256 + threadIdx.x;
  if (idx >= DIN * DOUT) return;
  const int k = idx / DOUT, n = idx % DOUT;
  Wt[n * DIN + k] = f2b(W[idx]);
}

__global__ __launch_bounds__(256) void k_pre(
    const int* __restrict__ ei, int* __restrict__ deg, int* __restrict__ bcnt,
    int2* __restrict__ bbuf, const float4* __restrict__ x4, ushort4* __restrict__ xb4,
    const float* __restrict__ W1, unsigned short* __restrict__ W1t,
    const float* __restrict__ W2, unsigned short* __restrict__ W2t,
    const float* __restrict__ W3, unsigned short* __restrict__ W3t)
{
  __shared__ int hcnt[NB];
  __shared__ int lpos[NB];
  int b = blockIdx.x;
  const int t = threadIdx.x;

  if (b < BBUCKET) {
    const int e0 = b * CHUNK;
    const int EP = NEDGES + NNODES;
    const int ecnt = min(CHUNK, EP - e0);
    for (int i = t; i < NB; i += 256) hcnt[i] = 0;
    __syncthreads();
    for (int i = t; i < ecnt; i += 256) {
      const int e = e0 + i;
      int dst = (e < NEDGES) ? ei[NEDGES + e] : (e - NEDGES);
      atomicAdd(&deg[dst], 1);
      atomicAdd(&hcnt[dst >> 8], 1);
    }
    __syncthreads();
    for (int bb = t; bb < NB; bb += 256) {
      const int c = hcnt[bb];
      lpos[bb] = (c > 0) ? atomicAdd(&bcnt[bb], c) : 0;
    }
    __syncthreads();
    for (int i = t; i < ecnt; i += 256) {
      const int e = e0 + i;
      int src, dst;
      if (e < NEDGES) { src = ei[e]; dst = ei[NEDGES + e]; }
      else            { src = e - NEDGES; dst = src; }
      const int bb = dst >> 8;
      const int p = atomicAdd(&lpos[bb], 1);
      bbuf[(size_t)bb * BCAP + p] = make_int2(src, dst);
    }
    return;
  }
  b -= BBUCKET;
  if (b < BCASTX) {
    const int n4 = NNODES * 512 / 4;
    for (int i = b * 256 + t; i < n4; i += BCASTX * 256) {
      float4 v = x4[i];
      ushort4 o;
      o.x = f2b(v.x); o.y = f2b(v.y); o.z = f2b(v.z); o.w = f2b(v.w);
      xb4[i] = o;
    }
    return;
  }
  b -= BCASTX;
  if (b < 512) { castW_body(b, 512, W1, W1t); return; }
  b -= 512;
  if (b < 256) { castW_body(b, 256, W2, W2t); return; }
  b -= 256;
  castW_body(b, 256, W3, W3t);
}

// ---------------- scans ----------------
__global__ __launch_bounds__(256) void k_scan1(const int* __restrict__ deg,
                                               int* __restrict__ rowptr,
                                               int* __restrict__ bsum) {
  __shared__ int wsum[4];
  const int t = threadIdx.x, lane = t & 63, w = t >> 6;
  const int i = blockIdx.x * 256 + t;
  int x = (i < NNODES) ? deg[i] : 0;
  #pragma unroll
  for (int off = 1; off < 64; off <<= 1) {
    int y = __shfl_up(x, off);
    if (lane >= off) x += y;
  }
  if (lane == 63) wsum[w] = x;
  __syncthreads();
  int s0 = wsum[0], s1 = wsum[1], s2 = wsum[2], s3 = wsum[3];
  int woff = (w > 0 ? s0 : 0) + (w > 1 ? s1 : 0) + (w > 2 ? s2 : 0);
  if (i < NNODES) rowptr[i + 1] = woff + x;
  if (t == 255) bsum[blockIdx.x] = woff + x;
}

// merged scan2+scan3: block b reduces bsum[0..b) itself, adds to its rowptr span
__global__ __launch_bounds__(256) void k_scan23(int* __restrict__ rowptr,
                                                const int* __restrict__ bsum) {
  __shared__ int wsum[4];
  const int b = blockIdx.x;
  const int t = threadIdx.x, lane = t & 63, w = t >> 6;
  int v = (t < b && t < SCANB) ? bsum[t] : 0;
  #pragma unroll
  for (int off = 32; off > 0; off >>= 1) v += __shfl_xor(v, off);
  if (lane == 0) wsum[w] = v;
  __syncthreads();
  const int excl = wsum[0] + wsum[1] + wsum[2] + wsum[3];
  const int i = b * 256 + t;
  if (i == 0) rowptr[0] = 0;
  if (i < NNODES) rowptr[i + 1] += excl;
}

// ---------------- GEMM body: H(sliced) = A @ W, + fused attention logits ----------------
// Hs layout: [NSLICE][NNODES][32] bf16 (slice = col>>5) so each 32-col slice is
// a contiguous 3.2MB region (per-XCD L2-resident for the sliced aggregation).
template<int DIN>
__device__ void gemm_body(int bid,
    const unsigned short* __restrict__ Ab, const unsigned short* __restrict__ Wt,
    const float* __restrict__ a_src, const float* __restrict__ a_dst,
    unsigned short* __restrict__ Hs, float* __restrict__ asn, float* __restrict__ adn,
    float (*s_ps)[64], float (*s_pd)[64])
{
  const int lane = threadIdx.x & 63;
  const int wv = threadIdx.x >> 6;
  const int row0 = bid * 64;
  const int col0 = wv * 64;
  const int lr = lane & 15;
  const int lk = lane >> 4;

  f32x4 acc[4][4];
  #pragma unroll
  for (int m = 0; m < 4; ++m)
    #pragma unroll
    for (int n = 0; n < 4; ++n)
      acc[m][n] = (f32x4){0.f, 0.f, 0.f, 0.f};

  const unsigned short* arow[4];
  #pragma unroll
  for (int m = 0; m < 4; ++m) {
    int r = row0 + m * 16 + lr;
    if (r > NNODES - 1) r = NNODES - 1;
    arow[m] = Ab + (size_t)r * DIN + lk * 8;
  }
  const unsigned short* brow[4];
  #pragma unroll
  for (int n = 0; n < 4; ++n)
    brow[n] = Wt + (size_t)(col0 + n * 16 + lr) * DIN + lk * 8;

  for (int k = 0; k < DIN; k += 32) {
    short8 aF[4], bF[4];
    #pragma unroll
    for (int m = 0; m < 4; ++m)
      aF[m] = *reinterpret_cast<const short8*>(arow[m] + k);
    #pragma unroll
    for (int n = 0; n < 4; ++n)
      bF[n] = *reinterpret_cast<const short8*>(brow[n] + k);
    #pragma unroll
    for (int m = 0; m < 4; ++m)
      #pragma unroll
      for (int n = 0; n < 4; ++n)
        acc[m][n] = __builtin_amdgcn_mfma_f32_16x16x32_bf16(aF[m], bF[n], acc[m][n], 0, 0, 0);
  }

  float asv[4], adv[4];
  #pragma unroll
  for (int n = 0; n < 4; ++n) {
    int c = col0 + n * 16 + lr;
    asv[n] = a_src[c];
    adv[n] = a_dst[c];
  }

  #pragma unroll
  for (int m = 0; m < 4; ++m) {
    float ps[4] = {0.f, 0.f, 0.f, 0.f};
    float pd[4] = {0.f, 0.f, 0.f, 0.f};
    #pragma unroll
    for (int n = 0; n < 4; ++n) {
      const int col = col0 + n * 16 + lr;
      const size_t sbase = (size_t)(col >> 5) * NNODES * 32 + (col & 31);
      #pragma unroll
      for (int j = 0; j < 4; ++j) {
        int row = row0 + m * 16 + lk * 4 + j;
        float v = acc[m][n][j];
        if (row < NNODES)
          Hs[sbase + (size_t)row * 32] = f2b(v);
        ps[j] = fmaf(v, asv[n], ps[j]);
        pd[j] = fmaf(v, adv[n], pd[j]);
      }
    }
    #pragma unroll
    for (int off = 1; off < 16; off <<= 1) {
      #pragma unroll
      for (int j = 0; j < 4; ++j) {
        ps[j] += __shfl_xor(ps[j], off);
        pd[j] += __shfl_xor(pd[j], off);
      }
    }
    if (lr == 0) {
      #pragma unroll
      for (int j = 0; j < 4; ++j) {
        s_ps[wv][m * 16 + lk * 4 + j] = ps[j];
        s_pd[wv][m * 16 + lk * 4 + j] = pd[j];
      }
    }
  }

  __syncthreads();
  const int t = threadIdx.x;
  if (t < 64) {
    int row = row0 + t;
    if (row < NNODES) {
      asn[row] = s_ps[0][t] + s_ps[1][t] + s_ps[2][t] + s_ps[3][t];
      adn[row] = s_pd[0][t] + s_pd[1][t] + s_pd[2][t] + s_pd[3][t];
    }
  }
}

template<int DIN>
__global__ __launch_bounds__(256) void k_gemm_mfma(
    const unsigned short* __restrict__ Ab, const unsigned short* __restrict__ Wt,
    const float* __restrict__ a_src, const float* __restrict__ a_dst,
    unsigned short* __restrict__ Hs, float* __restrict__ asn, float* __restrict__ adn)
{
  __shared__ float s_ps[4][64];
  __shared__ float s_pd[4][64];
  gemm_body<DIN>(blockIdx.x, Ab, Wt, a_src, a_dst, Hs, asn, adn, s_ps, s_pd);
}

// ---------------- fat mid kernel: unbucket || gemm1 ----------------
__global__ __launch_bounds__(256) void k_mid(
    const int2* __restrict__ bbuf, const int* __restrict__ bcnt,
    const int* __restrict__ rowptr, int* __restrict__ esrc,
    const unsigned short* __restrict__ Xb, const unsigned short* __restrict__ W1t,
    const float* __restrict__ a_src, const float* __restrict__ a_dst,
    unsigned short* __restrict__ Hs, float* __restrict__ asn, float* __restrict__ adn)
{
  __shared__ float s_ps[4][64];
  __shared__ float s_pd[4][64];
  __shared__ int fill[256];
  if (blockIdx.x < NB) {
    const int b = blockIdx.x;
    fill[threadIdx.x] = 0;
    __syncthreads();
    const int cnt = bcnt[b];
    const int2* __restrict__ bp = bbuf + (size_t)b * BCAP;
    for (int i = threadIdx.x; i < cnt; i += 256) {
      const int2 sd = bp[i];
      const int pos = rowptr[sd.y] + atomicAdd(&fill[sd.y & 255], 1);
      esrc[pos] = sd.x;
    }
    return;
  }
  gemm_body<512>(blockIdx.x - NB, Xb, W1t, a_src, a_dst, Hs, asn, adn, s_ps, s_pd);
}

// ---------------- per-edge attention weights (softmax) ----------------
// one wave per dst: per-dst (max, sum) then alpha[i] = exp(e - m) / s
__global__ __launch_bounds__(256) void k_alpha(
    const int* __restrict__ rowptr, const int* __restrict__ esrc,
    const float* __restrict__ asn, const float* __restrict__ adn,
    float* __restrict__ alpha)
{
  const int lane = threadIdx.x & 63;
  const int wv = threadIdx.x >> 6;
  const int n = blockIdx.x * 4 + wv;
  if (n >= NNODES) return;
  const int start = rowptr[n];
  const int end = rowptr[n + 1];
  const float adv = adn[n];

  float m = -1e30f, s = 0.f;
  for (int i = start + lane; i < end; i += 64) {
    const float e = lrelu(asn[esrc[i]] + adv);
    const float mn = fmaxf(m, e);
    s = s * __expf(m - mn) + __expf(e - mn);
    m = mn;
  }
  #pragma unroll
  for (int off = 32; off > 0; off >>= 1) {
    const float mo = __shfl_xor(m, off);
    const float so = __shfl_xor(s, off);
    const float mn = fmaxf(m, mo);
    s = s * __expf(m - mn) + so * __expf(mo - mn);
    m = mn;
  }
  const float inv = 1.f / (s + 1e-16f);
  for (int i = start + lane; i < end; i += 64)
    alpha[i] = __expf(lrelu(asn[esrc[i]] + adv) - m) * inv;
}

// ---------------- sliced aggregation ----------------
// block handles slice (blockIdx&7) of 4 dsts; slice s on XCD s (round-robin
// blockIdx->XCD) reads only Hs slice s = 3.2MB -> per-XCD L2-resident.
// Within a wave: edge-group eg=lane>>2 (16 edges/step), quad lane cj=lane&3
// owns 8 cols; per-edge read = one 64B line of the slice.
template<int MODE, int OUT32>
__global__ __launch_bounds__(256) void k_aggs(
    const unsigned short* __restrict__ Hs, const int* __restrict__ rowptr,
    const int* __restrict__ esrc, const float* __restrict__ alpha,
    const float* __restrict__ bias, const unsigned short* __restrict__ baseb,
    float* __restrict__ out, unsigned short* __restrict__ outb)
{
  const int slice = blockIdx.x & 7;
  const int grp = blockIdx.x >> 3;
  const int lane = threadIdx.x & 63;
  const int wv = threadIdx.x >> 6;
  const int n = grp * 4 + wv;
  if (n >= NNODES) return;
  const int start = rowptr[n];
  const int end = rowptr[n + 1];

  const int eg = lane >> 2;
  const int cj = lane & 3;
  const unsigned short* __restrict__ Hsl = Hs + (size_t)slice * NNODES * 32 + cj * 8;

  float acc[8];
  #pragma unroll
  for (int k = 0; k < 8; ++k) acc[k] = 0.f;

  for (int c0 = start; c0 < end; c0 += 16) {
    const int i = c0 + eg;
    if (i < end) {                       // quad-uniform branch
      const int sj = esrc[i];
      const float a = alpha[i];
      const u16x8 h = *reinterpret_cast<const u16x8*>(Hsl + (size_t)sj * 32);
      #pragma unroll
      for (int k = 0; k < 8; ++k)
        acc[k] = fmaf(a, b2f((unsigned short)h[k]), acc[k]);
    }
  }

  // combine the 16 edge-groups (lanes sharing cj)
  #pragma unroll
  for (int off = 4; off < 64; off <<= 1) {
    #pragma unroll
    for (int k = 0; k < 8; ++k) acc[k] += __shfl_xor(acc[k], off);
  }

  if (lane < 4) {
    const int cb = slice * 32 + cj * 8;
    float o[8];
    #pragma unroll
    for (int k = 0; k < 8; ++k) o[k] = fmaxf(acc[k] + bias[cb + k], 0.f);
    if (MODE == 1) {
      const u16x8 r = *reinterpret_cast<const u16x8*>(baseb + (size_t)n * DOUT + cb);
      #pragma unroll
      for (int k = 0; k < 8; ++k) o[k] += b2f((unsigned short)r[k]);
    }
    if (OUT32) {
      *reinterpret_cast<float4*>(out + (size_t)n * DOUT + cb)     = make_float4(o[0], o[1], o[2], o[3]);
      *reinterpret_cast<float4*>(out + (size_t)n * DOUT + cb + 4) = make_float4(o[4], o[5], o[6], o[7]);
    } else {
      u16x8 ob;
      #pragma unroll
      for (int k = 0; k < 8; ++k) ob[k] = f2b(o[k]);
      *reinterpret_cast<u16x8*>(outb + (size_t)n * DOUT + cb) = ob;
    }
  }
}

// ---------------- launch ----------------
extern "C" void kernel_launch(void* const* d_in, const int* in_sizes, int n_in,
                              void* d_out, int out_size, void* d_ws, size_t ws_size,
                              hipStream_t stream) {
  const float* x   = (const float*)d_in[0];
  const int*   ei  = (const int*)d_in[1];
  const float* W1  = (const float*)d_in[2];
  const float* as1 = (const float*)d_in[3];
  const float* ad1 = (const float*)d_in[4];
  const float* b1  = (const float*)d_in[5];
  const float* W2  = (const float*)d_in[6];
  const float* as2 = (const float*)d_in[7];
  const float* ad2 = (const float*)d_in[8];
  const float* b2  = (const float*)d_in[9];
  const float* W3  = (const float*)d_in[10];
  const float* as3 = (const float*)d_in[11];
  const float* ad3 = (const float*)d_in[12];
  const float* b3  = (const float*)d_in[13];
  float* out = (float*)d_out;

  char* ws = (char*)d_ws;
  size_t off = 0;
  auto alloc = [&](size_t bytes) -> void* {
    void* p = ws + off;
    off = (off + bytes + 255) & ~(size_t)255;
    return p;
  };
  unsigned short* Xb   = (unsigned short*)alloc((size_t)NNODES * 512 * sizeof(unsigned short));
  unsigned short* Hs   = (unsigned short*)alloc((size_t)NSLICE * NNODES * 32 * sizeof(unsigned short));
  unsigned short* W1t  = (unsigned short*)alloc((size_t)512 * DOUT * sizeof(unsigned short));
  unsigned short* W2t  = (unsigned short*)alloc((size_t)DOUT * DOUT * sizeof(unsigned short));
  unsigned short* W3t  = (unsigned short*)alloc((size_t)DOUT * DOUT * sizeof(unsigned short));
  float* asn  = (float*)alloc(NNODES * sizeof(float));
  float* adn  = (float*)alloc(NNODES * sizeof(float));
  float* alpha = (float*)alloc((size_t)(NEDGES + NNODES) * sizeof(float));
  int*   deg  = (int*)alloc(NNODES * sizeof(int) + NB * sizeof(int) + 256);
  int*   bcnt = deg + NNODES;
  int*   rowptr = (int*)alloc((NNODES + 1) * sizeof(int));
  int*   bsum = (int*)alloc(SCANB * sizeof(int));
  int*   esrc = (int*)alloc((size_t)(NEDGES + NNODES) * sizeof(int));
  int2*  bbuf = (int2*)alloc((size_t)NB * BCAP * sizeof(int2));

  hipMemsetAsync(deg, 0, (NNODES + NB) * sizeof(int), stream);

  // fat pre: bucket || castX || castW1-3
  const int preGrid = BBUCKET + BCASTX + 512 + 256 + 256;
  k_pre<<<preGrid, 256, 0, stream>>>(ei, deg, bcnt, bbuf,
                                     (const float4*)x, (ushort4*)Xb,
                                     W1, W1t, W2, W2t, W3, W3t);
  k_scan1<<<SCANB, 256, 0, stream>>>(deg, rowptr, bsum);
  k_scan23<<<SCANB, 256, 0, stream>>>(rowptr, bsum);

  // fat mid: unbucket || gemm layer 1 (sliced Hs out)
  k_mid<<<NB + GEMM_GRID, 256, 0, stream>>>(bbuf, bcnt, rowptr, esrc,
                                            Xb, W1t, as1, ad1, Hs, asn, adn);

  const int alphaGrid = (NNODES + 3) / 4;           // 12500
  const int aggsGrid  = alphaGrid * NSLICE;         // 100000

  // layer 1
  k_alpha<<<alphaGrid, 256, 0, stream>>>(rowptr, esrc, asn, adn, alpha);
  k_aggs<0, 0><<<aggsGrid, 256, 0, stream>>>(Hs, rowptr, esrc, alpha, b1, nullptr, nullptr, Xb);
  // layer 2
  k_gemm_mfma<256><<<GEMM_GRID, 256, 0, stream>>>(Xb, W2t, as2, ad2, Hs, asn, adn);
  k_alpha<<<alphaGrid, 256, 0, stream>>>(rowptr, esrc, asn, adn, alpha);
  k_aggs<1, 0><<<aggsGrid, 256, 0, stream>>>(Hs, rowptr, esrc, alpha, b2, Xb, nullptr, Xb);
  // layer 3
  k_gemm_mfma<256><<<GEMM_GRID, 256, 0, stream>>>(Xb, W3t, as3, ad3, Hs, asn, adn);
  k_alpha<<<alphaGrid, 256, 0, stream>>>(rowptr, esrc, asn, adn, alpha);
  k_aggs<1, 1><<<aggsGrid, 256, 0, stream>>>(Hs, rowptr, esrc, alpha, b3, Xb, out, nullptr);
}

// Round 14
// 809.764 us; speedup vs baseline: 1.0112x; 1.0112x over previous
//
#include <hip/hip_runtime.h>
#include <math.h>

#define NNODES 50000
#define NEDGES 1600000
#define DOUT 256
#define NEG_SLOPE 0.2f
#define SCANB ((NNODES + 255) / 256)
#define NB ((NNODES + 255) / 256)   // dst buckets of 256 nodes (196)
#define BCAP 10240                  // bucket capacity (mean ~8420, >15 sigma margin)
#define CHUNK 8192                  // edges per bucket block
#define BBUCKET ((NEDGES + NNODES + CHUNK - 1) / CHUNK)   // 202
#define BCASTX 2048
#define GEMM_GRID ((NNODES + 63) / 64)                    // 782
#define NSLICE 8                    // column slices (32 cols = 64B bf16 each)

typedef __attribute__((ext_vector_type(8))) short short8;
typedef __attribute__((ext_vector_type(8))) unsigned short u16x8;
typedef __attribute__((ext_vector_type(4))) float f32x4;
typedef __attribute__((ext_vector_type(2))) float f32x2;

__device__ __forceinline__ float lrelu(float e) { return e > 0.f ? e : NEG_SLOPE * e; }
__device__ __forceinline__ float b2f(unsigned short u) {
  union { unsigned u; float f; } c; c.u = ((unsigned)u) << 16; return c.f;
}
__device__ __forceinline__ float bitsf(unsigned u) {
  union { unsigned u; float f; } c; c.u = u; return c.f;
}
__device__ __forceinline__ unsigned short f2b(float f) {
  union { float f; unsigned u; } c; c.f = f;
  return (unsigned short)((c.u + 0x7fffu + ((c.u >> 16) & 1u)) >> 16);
}

// ---------------- fat pre kernel: bucket || castX || castW1-3 ----------------
__device__ void castW_body(int bid, int DIN, const float* __restrict__ W,
                           unsigned short* __restrict__ Wt) {
  const int idx = bid * 256 + threadIdx.x;
  if (idx >= DIN * DOUT) return;
  const int k = idx / DOUT, n = idx % DOUT;
  Wt[n * DIN + k] = f2b(W[idx]);
}

__global__ __launch_bounds__(256) void k_pre(
    const int* __restrict__ ei, int* __restrict__ deg, int* __restrict__ bcnt,
    int2* __restrict__ bbuf, const float4* __restrict__ x4, ushort4* __restrict__ xb4,
    const float* __restrict__ W1, unsigned short* __restrict__ W1t,
    const float* __restrict__ W2, unsigned short* __restrict__ W2t,
    const float* __restrict__ W3, unsigned short* __restrict__ W3t)
{
  __shared__ int hcnt[NB];
  __shared__ int lpos[NB];
  int b = blockIdx.x;
  const int t = threadIdx.x;

  if (b < BBUCKET) {
    const int e0 = b * CHUNK;
    const int EP = NEDGES + NNODES;
    const int ecnt = min(CHUNK, EP - e0);
    for (int i = t; i < NB; i += 256) hcnt[i] = 0;
    __syncthreads();
    for (int i = t; i < ecnt; i += 256) {
      const int e = e0 + i;
      int dst = (e < NEDGES) ? ei[NEDGES + e] : (e - NEDGES);
      atomicAdd(&deg[dst], 1);
      atomicAdd(&hcnt[dst >> 8], 1);
    }
    __syncthreads();
    for (int bb = t; bb < NB; bb += 256) {
      const int c = hcnt[bb];
      lpos[bb] = (c > 0) ? atomicAdd(&bcnt[bb], c) : 0;
    }
    __syncthreads();
    for (int i = t; i < ecnt; i += 256) {
      const int e = e0 + i;
      int src, dst;
      if (e < NEDGES) { src = ei[e]; dst = ei[NEDGES + e]; }
      else            { src = e - NEDGES; dst = src; }
      const int bb = dst >> 8;
      const int p = atomicAdd(&lpos[bb], 1);
      bbuf[(size_t)bb * BCAP + p] = make_int2(src, dst);
    }
    return;
  }
  b -= BBUCKET;
  if (b < BCASTX) {
    const int n4 = NNODES * 512 / 4;
    for (int i = b * 256 + t; i < n4; i += BCASTX * 256) {
      float4 v = x4[i];
      ushort4 o;
      o.x = f2b(v.x); o.y = f2b(v.y); o.z = f2b(v.z); o.w = f2b(v.w);
      xb4[i] = o;
    }
    return;
  }
  b -= BCASTX;
  if (b < 512) { castW_body(b, 512, W1, W1t); return; }
  b -= 512;
  if (b < 256) { castW_body(b, 256, W2, W2t); return; }
  b -= 256;
  castW_body(b, 256, W3, W3t);
}

// ---------------- scans ----------------
__global__ __launch_bounds__(256) void k_scan1(const int* __restrict__ deg,
                                               int* __restrict__ rowptr,
                                               int* __restrict__ bsum) {
  __shared__ int wsum[4];
  const int t = threadIdx.x, lane = t & 63, w = t >> 6;
  const int i = blockIdx.x * 256 + t;
  int x = (i < NNODES) ? deg[i] : 0;
  #pragma unroll
  for (int off = 1; off < 64; off <<= 1) {
    int y = __shfl_up(x, off);
    if (lane >= off) x += y;
  }
  if (lane == 63) wsum[w] = x;
  __syncthreads();
  int s0 = wsum[0], s1 = wsum[1], s2 = wsum[2], s3 = wsum[3];
  int woff = (w > 0 ? s0 : 0) + (w > 1 ? s1 : 0) + (w > 2 ? s2 : 0);
  if (i < NNODES) rowptr[i + 1] = woff + x;
  if (t == 255) bsum[blockIdx.x] = woff + x;
}

// merged scan2+scan3: block b reduces bsum[0..b) itself, adds to its rowptr span
__global__ __launch_bounds__(256) void k_scan23(int* __restrict__ rowptr,
                                                const int* __restrict__ bsum) {
  __shared__ int wsum[4];
  const int b = blockIdx.x;
  const int t = threadIdx.x, lane = t & 63, w = t >> 6;
  int v = (t < b && t < SCANB) ? bsum[t] : 0;
  #pragma unroll
  for (int off = 32; off > 0; off >>= 1) v += __shfl_xor(v, off);
  if (lane == 0) wsum[w] = v;
  __syncthreads();
  const int excl = wsum[0] + wsum[1] + wsum[2] + wsum[3];
  const int i = b * 256 + t;
  if (i == 0) rowptr[0] = 0;
  if (i < NNODES) rowptr[i + 1] += excl;
}

// ---------------- GEMM body: H(sliced) = A @ W, + fused attention logits ----------------
// Hs layout: [NSLICE][NNODES][32] bf16 (slice = col>>5): each slice contiguous
// 3.2MB -> per-XCD L2-resident for the sliced aggregation.
template<int DIN>
__device__ void gemm_body(int bid,
    const unsigned short* __restrict__ Ab, const unsigned short* __restrict__ Wt,
    const float* __restrict__ a_src, const float* __restrict__ a_dst,
    unsigned short* __restrict__ Hs, float* __restrict__ asn, float* __restrict__ adn,
    float (*s_ps)[64], float (*s_pd)[64])
{
  const int lane = threadIdx.x & 63;
  const int wv = threadIdx.x >> 6;
  const int row0 = bid * 64;
  const int col0 = wv * 64;
  const int lr = lane & 15;
  const int lk = lane >> 4;

  f32x4 acc[4][4];
  #pragma unroll
  for (int m = 0; m < 4; ++m)
    #pragma unroll
    for (int n = 0; n < 4; ++n)
      acc[m][n] = (f32x4){0.f, 0.f, 0.f, 0.f};

  const unsigned short* arow[4];
  #pragma unroll
  for (int m = 0; m < 4; ++m) {
    int r = row0 + m * 16 + lr;
    if (r > NNODES - 1) r = NNODES - 1;
    arow[m] = Ab + (size_t)r * DIN + lk * 8;
  }
  const unsigned short* brow[4];
  #pragma unroll
  for (int n = 0; n < 4; ++n)
    brow[n] = Wt + (size_t)(col0 + n * 16 + lr) * DIN + lk * 8;

  for (int k = 0; k < DIN; k += 32) {
    short8 aF[4], bF[4];
    #pragma unroll
    for (int m = 0; m < 4; ++m)
      aF[m] = *reinterpret_cast<const short8*>(arow[m] + k);
    #pragma unroll
    for (int n = 0; n < 4; ++n)
      bF[n] = *reinterpret_cast<const short8*>(brow[n] + k);
    #pragma unroll
    for (int m = 0; m < 4; ++m)
      #pragma unroll
      for (int n = 0; n < 4; ++n)
        acc[m][n] = __builtin_amdgcn_mfma_f32_16x16x32_bf16(aF[m], bF[n], acc[m][n], 0, 0, 0);
  }

  float asv[4], adv[4];
  #pragma unroll
  for (int n = 0; n < 4; ++n) {
    int c = col0 + n * 16 + lr;
    asv[n] = a_src[c];
    adv[n] = a_dst[c];
  }

  #pragma unroll
  for (int m = 0; m < 4; ++m) {
    float ps[4] = {0.f, 0.f, 0.f, 0.f};
    float pd[4] = {0.f, 0.f, 0.f, 0.f};
    #pragma unroll
    for (int n = 0; n < 4; ++n) {
      const int col = col0 + n * 16 + lr;
      const size_t sbase = (size_t)(col >> 5) * NNODES * 32 + (col & 31);
      #pragma unroll
      for (int j = 0; j < 4; ++j) {
        int row = row0 + m * 16 + lk * 4 + j;
        float v = acc[m][n][j];
        if (row < NNODES)
          Hs[sbase + (size_t)row * 32] = f2b(v);
        ps[j] = fmaf(v, asv[n], ps[j]);
        pd[j] = fmaf(v, adv[n], pd[j]);
      }
    }
    #pragma unroll
    for (int off = 1; off < 16; off <<= 1) {
      #pragma unroll
      for (int j = 0; j < 4; ++j) {
        ps[j] += __shfl_xor(ps[j], off);
        pd[j] += __shfl_xor(pd[j], off);
      }
    }
    if (lr == 0) {
      #pragma unroll
      for (int j = 0; j < 4; ++j) {
        s_ps[wv][m * 16 + lk * 4 + j] = ps[j];
        s_pd[wv][m * 16 + lk * 4 + j] = pd[j];
      }
    }
  }

  __syncthreads();
  const int t = threadIdx.x;
  if (t < 64) {
    int row = row0 + t;
    if (row < NNODES) {
      asn[row] = s_ps[0][t] + s_ps[1][t] + s_ps[2][t] + s_ps[3][t];
      adn[row] = s_pd[0][t] + s_pd[1][t] + s_pd[2][t] + s_pd[3][t];
    }
  }
}

template<int DIN>
__global__ __launch_bounds__(256) void k_gemm_mfma(
    const unsigned short* __restrict__ Ab, const unsigned short* __restrict__ Wt,
    const float* __restrict__ a_src, const float* __restrict__ a_dst,
    unsigned short* __restrict__ Hs, float* __restrict__ asn, float* __restrict__ adn)
{
  __shared__ float s_ps[4][64];
  __shared__ float s_pd[4][64];
  gemm_body<DIN>(blockIdx.x, Ab, Wt, a_src, a_dst, Hs, asn, adn, s_ps, s_pd);
}

// ---------------- fat mid kernel: unbucket || gemm1 ----------------
__global__ __launch_bounds__(256) void k_mid(
    const int2* __restrict__ bbuf, const int* __restrict__ bcnt,
    const int* __restrict__ rowptr, int* __restrict__ esrc,
    const unsigned short* __restrict__ Xb, const unsigned short* __restrict__ W1t,
    const float* __restrict__ a_src, const float* __restrict__ a_dst,
    unsigned short* __restrict__ Hs, float* __restrict__ asn, float* __restrict__ adn)
{
  __shared__ float s_ps[4][64];
  __shared__ float s_pd[4][64];
  __shared__ int fill[256];
  if (blockIdx.x < NB) {
    const int b = blockIdx.x;
    fill[threadIdx.x] = 0;
    __syncthreads();
    const int cnt = bcnt[b];
    const int2* __restrict__ bp = bbuf + (size_t)b * BCAP;
    for (int i = threadIdx.x; i < cnt; i += 256) {
      const int2 sd = bp[i];
      const int pos = rowptr[sd.y] + atomicAdd(&fill[sd.y & 255], 1);
      esrc[pos] = sd.x;
    }
    return;
  }
  gemm_body<512>(blockIdx.x - NB, Xb, W1t, a_src, a_dst, Hs, asn, adn, s_ps, s_pd);
}

// ---------------- per-edge attention weights (softmax) ----------------
__global__ __launch_bounds__(256) void k_alpha(
    const int* __restrict__ rowptr, const int* __restrict__ esrc,
    const float* __restrict__ asn, const float* __restrict__ adn,
    float* __restrict__ alpha)
{
  const int lane = threadIdx.x & 63;
  const int wv = threadIdx.x >> 6;
  const int n = blockIdx.x * 4 + wv;
  if (n >= NNODES) return;
  const int start = rowptr[n];
  const int end = rowptr[n + 1];
  const float adv = adn[n];

  float m = -1e30f, s = 0.f;
  for (int i = start + lane; i < end; i += 64) {
    const float e = lrelu(asn[esrc[i]] + adv);
    const float mn = fmaxf(m, e);
    s = s * __expf(m - mn) + __expf(e - mn);
    m = mn;
  }
  #pragma unroll
  for (int off = 32; off > 0; off >>= 1) {
    const float mo = __shfl_xor(m, off);
    const float so = __shfl_xor(s, off);
    const float mn = fmaxf(m, mo);
    s = s * __expf(m - mn) + so * __expf(mo - mn);
    m = mn;
  }
  const float inv = 1.f / (s + 1e-16f);
  for (int i = start + lane; i < end; i += 64)
    alpha[i] = __expf(lrelu(asn[esrc[i]] + adv) - m) * inv;
}

// ---------------- sliced aggregation v2 (coalesced loads + shfl broadcast) ----------------
// wave = (dst n, slice). Per 64-edge chunk: coalesced esrc/alpha load by all
// lanes, then 16-edge sub-steps broadcasting (src, a) via shfl (LDS pipe).
// Invalid lanes carry a=0 and gather row 0 (harmless, cache-hot).
template<int MODE, int OUT32>
__global__ __launch_bounds__(256) void k_aggs(
    const unsigned short* __restrict__ Hs, const int* __restrict__ rowptr,
    const int* __restrict__ esrc, const float* __restrict__ alpha,
    const float* __restrict__ bias, const unsigned short* __restrict__ baseb,
    float* __restrict__ out, unsigned short* __restrict__ outb)
{
  const int slice = blockIdx.x & 7;
  const int grp = blockIdx.x >> 3;
  const int lane = threadIdx.x & 63;
  const int wv = threadIdx.x >> 6;
  const int n = grp * 4 + wv;
  if (n >= NNODES) return;
  const int start = rowptr[n];
  const int end = rowptr[n + 1];

  const int eg = lane >> 2;      // edge sub-lane 0..15
  const int cj = lane & 3;       // col quad: 8 cols = 16B
  const unsigned short* __restrict__ Hsl = Hs + (size_t)slice * NNODES * 32 + cj * 8;

  f32x2 acc2[4];
  #pragma unroll
  for (int j = 0; j < 4; ++j) acc2[j] = (f32x2){0.f, 0.f};

  for (int c0 = start; c0 < end; c0 += 64) {
    const int i = c0 + lane;
    int msrc = 0;
    float mal = 0.f;
    if (i < end) { msrc = esrc[i]; mal = alpha[i]; }   // coalesced
    const int cnt = min(64, end - c0);
    const int nsub = (cnt + 15) >> 4;
    for (int jj = 0; jj < nsub; ++jj) {
      const int sel = jj * 16 + eg;
      const float a = __shfl(mal, sel);
      const int sj = __shfl(msrc, sel);
      const uint4 h = *reinterpret_cast<const uint4*>(Hsl + (size_t)sj * 32);
      const f32x2 a2 = {a, a};
      f32x2 h2;
      h2.x = bitsf(h.x << 16); h2.y = bitsf(h.x & 0xffff0000u);
      acc2[0] += a2 * h2;
      h2.x = bitsf(h.y << 16); h2.y = bitsf(h.y & 0xffff0000u);
      acc2[1] += a2 * h2;
      h2.x = bitsf(h.z << 16); h2.y = bitsf(h.z & 0xffff0000u);
      acc2[2] += a2 * h2;
      h2.x = bitsf(h.w << 16); h2.y = bitsf(h.w & 0xffff0000u);
      acc2[3] += a2 * h2;
    }
  }

  // combine the 16 edge sub-lanes (lanes sharing cj)
  #pragma unroll
  for (int off = 4; off < 64; off <<= 1) {
    #pragma unroll
    for (int j = 0; j < 4; ++j) {
      acc2[j].x += __shfl_xor(acc2[j].x, off);
      acc2[j].y += __shfl_xor(acc2[j].y, off);
    }
  }

  if (lane < 4) {
    const int cb = slice * 32 + cj * 8;
    float o[8];
    #pragma unroll
    for (int j = 0; j < 4; ++j) {
      o[2 * j]     = fmaxf(acc2[j].x + bias[cb + 2 * j], 0.f);
      o[2 * j + 1] = fmaxf(acc2[j].y + bias[cb + 2 * j + 1], 0.f);
    }
    if (MODE == 1) {
      const u16x8 r = *reinterpret_cast<const u16x8*>(baseb + (size_t)n * DOUT + cb);
      #pragma unroll
      for (int k = 0; k < 8; ++k) o[k] += b2f((unsigned short)r[k]);
    }
    if (OUT32) {
      *reinterpret_cast<float4*>(out + (size_t)n * DOUT + cb)     = make_float4(o[0], o[1], o[2], o[3]);
      *reinterpret_cast<float4*>(out + (size_t)n * DOUT + cb + 4) = make_float4(o[4], o[5], o[6], o[7]);
    } else {
      u16x8 ob;
      #pragma unroll
      for (int k = 0; k < 8; ++k) ob[k] = f2b(o[k]);
      *reinterpret_cast<u16x8*>(outb + (size_t)n * DOUT + cb) = ob;
    }
  }
}

// ---------------- launch ----------------
extern "C" void kernel_launch(void* const* d_in, const int* in_sizes, int n_in,
                              void* d_out, int out_size, void* d_ws, size_t ws_size,
                              hipStream_t stream) {
  const float* x   = (const float*)d_in[0];
  const int*   ei  = (const int*)d_in[1];
  const float* W1  = (const float*)d_in[2];
  const float* as1 = (const float*)d_in[3];
  const float* ad1 = (const float*)d_in[4];
  const float* b1  = (const float*)d_in[5];
  const float* W2  = (const float*)d_in[6];
  const float* as2 = (const float*)d_in[7];
  const float* ad2 = (const float*)d_in[8];
  const float* b2  = (const float*)d_in[9];
  const float* W3  = (const float*)d_in[10];
  const float* as3 = (const float*)d_in[11];
  const float* ad3 = (const float*)d_in[12];
  const float* b3  = (const float*)d_in[13];
  float* out = (float*)d_out;

  char* ws = (char*)d_ws;
  size_t off = 0;
  auto alloc = [&](size_t bytes) -> void* {
    void* p = ws + off;
    off = (off + bytes + 255) & ~(size_t)255;
    return p;
  };
  unsigned short* Xb   = (unsigned short*)alloc((size_t)NNODES * 512 * sizeof(unsigned short));
  unsigned short* Hs   = (unsigned short*)alloc((size_t)NSLICE * NNODES * 32 * sizeof(unsigned short));
  unsigned short* W1t  = (unsigned short*)alloc((size_t)512 * DOUT * sizeof(unsigned short));
  unsigned short* W2t  = (unsigned short*)alloc((size_t)DOUT * DOUT * sizeof(unsigned short));
  unsigned short* W3t  = (unsigned short*)alloc((size_t)DOUT * DOUT * sizeof(unsigned short));
  float* asn  = (float*)alloc(NNODES * sizeof(float));
  float* adn  = (float*)alloc(NNODES * sizeof(float));
  float* alpha = (float*)alloc((size_t)(NEDGES + NNODES) * sizeof(float));
  int*   deg  = (int*)alloc(NNODES * sizeof(int) + NB * sizeof(int) + 256);
  int*   bcnt = deg + NNODES;
  int*   rowptr = (int*)alloc((NNODES + 1) * sizeof(int));
  int*   bsum = (int*)alloc(SCANB * sizeof(int));
  int*   esrc = (int*)alloc((size_t)(NEDGES + NNODES) * sizeof(int));
  int2*  bbuf = (int2*)alloc((size_t)NB * BCAP * sizeof(int2));

  hipMemsetAsync(deg, 0, (NNODES + NB) * sizeof(int), stream);

  // fat pre: bucket || castX || castW1-3
  const int preGrid = BBUCKET + BCASTX + 512 + 256 + 256;
  k_pre<<<preGrid, 256, 0, stream>>>(ei, deg, bcnt, bbuf,
                                     (const float4*)x, (ushort4*)Xb,
                                     W1, W1t, W2, W2t, W3, W3t);
  k_scan1<<<SCANB, 256, 0, stream>>>(deg, rowptr, bsum);
  k_scan23<<<SCANB, 256, 0, stream>>>(rowptr, bsum);

  // fat mid: unbucket || gemm layer 1 (sliced Hs out)
  k_mid<<<NB + GEMM_GRID, 256, 0, stream>>>(bbuf, bcnt, rowptr, esrc,
                                            Xb, W1t, as1, ad1, Hs, asn, adn);

  const int alphaGrid = (NNODES + 3) / 4;           // 12500
  const int aggsGrid  = alphaGrid * NSLICE;         // 100000

  // layer 1
  k_alpha<<<alphaGrid, 256, 0, stream>>>(rowptr, esrc, asn, adn, alpha);
  k_aggs<0, 0><<<aggsGrid, 256, 0, stream>>>(Hs, rowptr, esrc, alpha, b1, nullptr, nullptr, Xb);
  // layer 2
  k_gemm_mfma<256><<<GEMM_GRID, 256, 0, stream>>>(Xb, W2t, as2, ad2, Hs, asn, adn);
  k_alpha<<<alphaGrid, 256, 0, stream>>>(rowptr, esrc, asn, adn, alpha);
  k_aggs<1, 0><<<aggsGrid, 256, 0, stream>>>(Hs, rowptr, esrc, alpha, b2, Xb, nullptr, Xb);
  // layer 3
  k_gemm_mfma<256><<<GEMM_GRID, 256, 0, stream>>>(Xb, W3t, as3, ad3, Hs, asn, adn);
  k_alpha<<<alphaGrid, 256, 0, stream>>>(rowptr, esrc, asn, adn, alpha);
  k_aggs<1, 1><<<aggsGrid, 256, 0, stream>>>(Hs, rowptr, esrc, alpha, b3, Xb, out, nullptr);
}

// Round 15
// 573.916 us; speedup vs baseline: 1.4268x; 1.4109x over previous
//
#include <hip/hip_runtime.h>
#include <math.h>

#define NNODES 50000
#define NEDGES 1600000
#define DOUT 256
#define NEG_SLOPE 0.2f
#define SCANB ((NNODES + 255) / 256)
#define NB ((NNODES + 255) / 256)   // dst buckets of 256 nodes (196)
#define BCAP 10240                  // bucket capacity (mean ~8420, >15 sigma margin)
#define CHUNK 8192                  // edges per bucket block
#define BBUCKET ((NEDGES + NNODES + CHUNK - 1) / CHUNK)   // 202
#define BCASTX 2048
#define GEMM_GRID ((NNODES + 63) / 64)                    // 782

typedef __attribute__((ext_vector_type(8))) short short8;
typedef __attribute__((ext_vector_type(8))) unsigned short u16x8;
typedef __attribute__((ext_vector_type(4))) float f32x4;

__device__ __forceinline__ float lrelu(float e) { return e > 0.f ? e : NEG_SLOPE * e; }
__device__ __forceinline__ float b2f(unsigned short u) {
  union { unsigned u; float f; } c; c.u = ((unsigned)u) << 16; return c.f;
}
__device__ __forceinline__ unsigned short f2b(float f) {
  union { float f; unsigned u; } c; c.f = f;
  return (unsigned short)((c.u + 0x7fffu + ((c.u >> 16) & 1u)) >> 16);
}

// ---------------- fat pre kernel: bucket || castX || castW1-3 ----------------
__device__ void castW_body(int bid, int DIN, const float* __restrict__ W,
                           unsigned short* __restrict__ Wt) {
  const int idx = bid * 256 + threadIdx.x;
  if (idx >= DIN * DOUT) return;
  const int k = idx / DOUT, n = idx % DOUT;
  Wt[n * DIN + k] = f2b(W[idx]);
}

__global__ __launch_bounds__(256) void k_pre(
    const int* __restrict__ ei, int* __restrict__ deg, int* __restrict__ bcnt,
    int2* __restrict__ bbuf, const float4* __restrict__ x4, ushort4* __restrict__ xb4,
    const float* __restrict__ W1, unsigned short* __restrict__ W1t,
    const float* __restrict__ W2, unsigned short* __restrict__ W2t,
    const float* __restrict__ W3, unsigned short* __restrict__ W3t)
{
  __shared__ int hcnt[NB];
  __shared__ int lpos[NB];
  int b = blockIdx.x;
  const int t = threadIdx.x;

  if (b < BBUCKET) {
    // bucket: per-block LDS histogram -> one reserve atomic per (block,bucket)
    // -> block-private contiguous sub-segment writes (L2-merged lines).
    const int e0 = b * CHUNK;
    const int EP = NEDGES + NNODES;
    const int ecnt = min(CHUNK, EP - e0);
    for (int i = t; i < NB; i += 256) hcnt[i] = 0;
    __syncthreads();
    for (int i = t; i < ecnt; i += 256) {
      const int e = e0 + i;
      int dst = (e < NEDGES) ? ei[NEDGES + e] : (e - NEDGES);
      atomicAdd(&deg[dst], 1);
      atomicAdd(&hcnt[dst >> 8], 1);
    }
    __syncthreads();
    for (int bb = t; bb < NB; bb += 256) {
      const int c = hcnt[bb];
      lpos[bb] = (c > 0) ? atomicAdd(&bcnt[bb], c) : 0;
    }
    __syncthreads();
    for (int i = t; i < ecnt; i += 256) {
      const int e = e0 + i;
      int src, dst;
      if (e < NEDGES) { src = ei[e]; dst = ei[NEDGES + e]; }
      else            { src = e - NEDGES; dst = src; }
      const int bb = dst >> 8;
      const int p = atomicAdd(&lpos[bb], 1);
      bbuf[(size_t)bb * BCAP + p] = make_int2(src, dst);
    }
    return;
  }
  b -= BBUCKET;
  if (b < BCASTX) {
    const int n4 = NNODES * 512 / 4;
    for (int i = b * 256 + t; i < n4; i += BCASTX * 256) {
      float4 v = x4[i];
      ushort4 o;
      o.x = f2b(v.x); o.y = f2b(v.y); o.z = f2b(v.z); o.w = f2b(v.w);
      xb4[i] = o;
    }
    return;
  }
  b -= BCASTX;
  if (b < 512) { castW_body(b, 512, W1, W1t); return; }
  b -= 512;
  if (b < 256) { castW_body(b, 256, W2, W2t); return; }
  b -= 256;
  castW_body(b, 256, W3, W3t);
}

// ---------------- scans ----------------
__global__ __launch_bounds__(256) void k_scan1(const int* __restrict__ deg,
                                               int* __restrict__ rowptr,
                                               int* __restrict__ bsum) {
  __shared__ int wsum[4];
  const int t = threadIdx.x, lane = t & 63, w = t >> 6;
  const int i = blockIdx.x * 256 + t;
  int x = (i < NNODES) ? deg[i] : 0;
  #pragma unroll
  for (int off = 1; off < 64; off <<= 1) {
    int y = __shfl_up(x, off);
    if (lane >= off) x += y;
  }
  if (lane == 63) wsum[w] = x;
  __syncthreads();
  int s0 = wsum[0], s1 = wsum[1], s2 = wsum[2], s3 = wsum[3];
  int woff = (w > 0 ? s0 : 0) + (w > 1 ? s1 : 0) + (w > 2 ? s2 : 0);
  if (i < NNODES) rowptr[i + 1] = woff + x;
  if (t == 255) bsum[blockIdx.x] = woff + x;
}

// merged scan2+scan3: block b reduces bsum[0..b) itself, adds to its rowptr span
__global__ __launch_bounds__(256) void k_scan23(int* __restrict__ rowptr,
                                                const int* __restrict__ bsum) {
  __shared__ int wsum[4];
  const int b = blockIdx.x;
  const int t = threadIdx.x, lane = t & 63, w = t >> 6;
  int v = (t < b && t < SCANB) ? bsum[t] : 0;
  #pragma unroll
  for (int off = 32; off > 0; off >>= 1) v += __shfl_xor(v, off);
  if (lane == 0) wsum[w] = v;
  __syncthreads();
  const int excl = wsum[0] + wsum[1] + wsum[2] + wsum[3];
  const int i = b * 256 + t;
  if (i == 0) rowptr[0] = 0;
  if (i < NNODES) rowptr[i + 1] += excl;
}

// ---------------- GEMM body (device): H = A @ W + fused attention logits ----------------
template<int DIN>
__device__ void gemm_body(int bid,
    const unsigned short* __restrict__ Ab, const unsigned short* __restrict__ Wt,
    const float* __restrict__ a_src, const float* __restrict__ a_dst,
    unsigned short* __restrict__ Hb, float* __restrict__ asn, float* __restrict__ adn,
    float (*s_ps)[64], float (*s_pd)[64])
{
  const int lane = threadIdx.x & 63;
  const int wv = threadIdx.x >> 6;
  const int row0 = bid * 64;
  const int col0 = wv * 64;
  const int lr = lane & 15;
  const int lk = lane >> 4;

  f32x4 acc[4][4];
  #pragma unroll
  for (int m = 0; m < 4; ++m)
    #pragma unroll
    for (int n = 0; n < 4; ++n)
      acc[m][n] = (f32x4){0.f, 0.f, 0.f, 0.f};

  const unsigned short* arow[4];
  #pragma unroll
  for (int m = 0; m < 4; ++m) {
    int r = row0 + m * 16 + lr;
    if (r > NNODES - 1) r = NNODES - 1;
    arow[m] = Ab + (size_t)r * DIN + lk * 8;
  }
  const unsigned short* brow[4];
  #pragma unroll
  for (int n = 0; n < 4; ++n)
    brow[n] = Wt + (size_t)(col0 + n * 16 + lr) * DIN + lk * 8;

  for (int k = 0; k < DIN; k += 32) {
    short8 aF[4], bF[4];
    #pragma unroll
    for (int m = 0; m < 4; ++m)
      aF[m] = *reinterpret_cast<const short8*>(arow[m] + k);
    #pragma unroll
    for (int n = 0; n < 4; ++n)
      bF[n] = *reinterpret_cast<const short8*>(brow[n] + k);
    #pragma unroll
    for (int m = 0; m < 4; ++m)
      #pragma unroll
      for (int n = 0; n < 4; ++n)
        acc[m][n] = __builtin_amdgcn_mfma_f32_16x16x32_bf16(aF[m], bF[n], acc[m][n], 0, 0, 0);
  }

  float asv[4], adv[4];
  #pragma unroll
  for (int n = 0; n < 4; ++n) {
    int c = col0 + n * 16 + lr;
    asv[n] = a_src[c];
    adv[n] = a_dst[c];
  }

  #pragma unroll
  for (int m = 0; m < 4; ++m) {
    float ps[4] = {0.f, 0.f, 0.f, 0.f};
    float pd[4] = {0.f, 0.f, 0.f, 0.f};
    #pragma unroll
    for (int n = 0; n < 4; ++n) {
      int col = col0 + n * 16 + lr;
      #pragma unroll
      for (int j = 0; j < 4; ++j) {
        int row = row0 + m * 16 + lk * 4 + j;
        float v = acc[m][n][j];
        if (row < NNODES)
          Hb[(size_t)row * DOUT + col] = f2b(v);
        ps[j] = fmaf(v, asv[n], ps[j]);
        pd[j] = fmaf(v, adv[n], pd[j]);
      }
    }
    #pragma unroll
    for (int off = 1; off < 16; off <<= 1) {
      #pragma unroll
      for (int j = 0; j < 4; ++j) {
        ps[j] += __shfl_xor(ps[j], off);
        pd[j] += __shfl_xor(pd[j], off);
      }
    }
    if (lr == 0) {
      #pragma unroll
      for (int j = 0; j < 4; ++j) {
        s_ps[wv][m * 16 + lk * 4 + j] = ps[j];
        s_pd[wv][m * 16 + lk * 4 + j] = pd[j];
      }
    }
  }

  __syncthreads();
  const int t = threadIdx.x;
  if (t < 64) {
    int row = row0 + t;
    if (row < NNODES) {
      asn[row] = s_ps[0][t] + s_ps[1][t] + s_ps[2][t] + s_ps[3][t];
      adn[row] = s_pd[0][t] + s_pd[1][t] + s_pd[2][t] + s_pd[3][t];
    }
  }
}

// standalone gemm (layers 2,3)
template<int DIN>
__global__ __launch_bounds__(256) void k_gemm_mfma(
    const unsigned short* __restrict__ Ab, const unsigned short* __restrict__ Wt,
    const float* __restrict__ a_src, const float* __restrict__ a_dst,
    unsigned short* __restrict__ Hb, float* __restrict__ asn, float* __restrict__ adn)
{
  __shared__ float s_ps[4][64];
  __shared__ float s_pd[4][64];
  gemm_body<DIN>(blockIdx.x, Ab, Wt, a_src, a_dst, Hb, asn, adn, s_ps, s_pd);
}

// ---------------- fat mid kernel: unbucket || gemm1 ----------------
__global__ __launch_bounds__(256) void k_mid(
    const int2* __restrict__ bbuf, const int* __restrict__ bcnt,
    const int* __restrict__ rowptr, int* __restrict__ esrc,
    const unsigned short* __restrict__ Xb, const unsigned short* __restrict__ W1t,
    const float* __restrict__ a_src, const float* __restrict__ a_dst,
    unsigned short* __restrict__ Hb, float* __restrict__ asn, float* __restrict__ adn)
{
  __shared__ float s_ps[4][64];
  __shared__ float s_pd[4][64];
  __shared__ int fill[256];
  if (blockIdx.x < NB) {
    // unbucket: contiguous esrc region per block -> L2-merged writes
    const int b = blockIdx.x;
    fill[threadIdx.x] = 0;
    __syncthreads();
    const int cnt = bcnt[b];
    const int2* __restrict__ bp = bbuf + (size_t)b * BCAP;
    for (int i = threadIdx.x; i < cnt; i += 256) {
      const int2 sd = bp[i];
      const int pos = rowptr[sd.y] + atomicAdd(&fill[sd.y & 255], 1);
      esrc[pos] = sd.x;
    }
    return;
  }
  gemm_body<512>(blockIdx.x - NB, Xb, W1t, a_src, a_dst, Hb, asn, adn, s_ps, s_pd);
}

// ---------------- attention softmax + aggregation (single sweep) ----------------
// Residual chain kept in bf16: MODE=1 reads bf16 base; OUT32=1 writes the final
// fp32 output (layer 3), otherwise only the bf16 row (next layer's GEMM input).
template<int MODE, int OUT32>
__global__ __launch_bounds__(256) void k_agg(
    const unsigned short* __restrict__ Hb, const int* __restrict__ rowptr,
    const int* __restrict__ esrc, const float* __restrict__ asn,
    const float* __restrict__ adn, const float* __restrict__ bias,
    const unsigned short* __restrict__ baseb, float* __restrict__ out,
    unsigned short* __restrict__ outb)
{
  const int lane = threadIdx.x & 63;
  const int wv = threadIdx.x >> 6;
  const int n = blockIdx.x * 4 + wv;
  if (n >= NNODES) return;
  const int start = rowptr[n];
  const int end = rowptr[n + 1];
  const float adv = adn[n];

  const int q = lane >> 4;
  const int c16 = lane & 15;
  const unsigned short* __restrict__ hb0 = Hb + c16 * 8;
  const unsigned short* __restrict__ hb1 = Hb + 128 + c16 * 8;

  float m = -1e30f, s = 0.f;
  float acc[16];
  #pragma unroll
  for (int k = 0; k < 16; ++k) acc[k] = 0.f;

  for (int c0 = start; c0 < end; c0 += 64) {
    const int i = c0 + lane;
    int msrc = 0;
    float e = -1e30f;
    if (i < end) {
      msrc = esrc[i];
      e = lrelu(asn[msrc] + adv);
    }
    float cm = e;
    #pragma unroll
    for (int off = 32; off > 0; off >>= 1) cm = fmaxf(cm, __shfl_xor(cm, off));
    const float mn = fmaxf(m, cm);
    const float resc = __expf(m - mn);
    s *= resc;
    #pragma unroll
    for (int k = 0; k < 16; ++k) acc[k] *= resc;
    m = mn;
    float p = __expf(e - mn);
    float cs = p;
    #pragma unroll
    for (int off = 32; off > 0; off >>= 1) cs += __shfl_xor(cs, off);
    s += cs;

    const int cnt = min(64, end - c0);
    const int qcnt = (cnt + 3) >> 2;
    for (int jj = 0; jj < qcnt; jj += 2) {
      const int e0 = 4 * jj + q;
      const int e1 = e0 + 4;
      const int s0 = (e0 < cnt) ? e0 : 0;
      const int s1 = (e1 < cnt) ? e1 : 0;
      float a0 = __shfl(p, s0);
      const int sj0 = __shfl(msrc, s0);
      float a1 = __shfl(p, s1);
      const int sj1 = __shfl(msrc, s1);
      if (e0 >= cnt) a0 = 0.f;
      if (jj + 1 >= qcnt || e1 >= cnt) a1 = 0.f;
      if (a0 != 0.f) {
        const u16x8 h00 = *reinterpret_cast<const u16x8*>(hb0 + (size_t)sj0 * DOUT);
        const u16x8 h01 = *reinterpret_cast<const u16x8*>(hb1 + (size_t)sj0 * DOUT);
        #pragma unroll
        for (int k = 0; k < 8; ++k) {
          acc[k]     = fmaf(a0, b2f((unsigned short)h00[k]), acc[k]);
          acc[k + 8] = fmaf(a0, b2f((unsigned short)h01[k]), acc[k + 8]);
        }
      }
      if (a1 != 0.f) {
        const u16x8 h10 = *reinterpret_cast<const u16x8*>(hb0 + (size_t)sj1 * DOUT);
        const u16x8 h11 = *reinterpret_cast<const u16x8*>(hb1 + (size_t)sj1 * DOUT);
        #pragma unroll
        for (int k = 0; k < 8; ++k) {
          acc[k]     = fmaf(a1, b2f((unsigned short)h10[k]), acc[k]);
          acc[k + 8] = fmaf(a1, b2f((unsigned short)h11[k]), acc[k + 8]);
        }
      }
    }
  }

  #pragma unroll
  for (int k = 0; k < 16; ++k) {
    acc[k] += __shfl_xor(acc[k], 16);
    acc[k] += __shfl_xor(acc[k], 32);
  }

  if (lane < 16) {
    const float inv = 1.f / (s + 1e-16f);
    const int cb = c16 * 8;
    float o[16];
    #pragma unroll
    for (int k = 0; k < 8; ++k) {
      o[k]     = fmaxf(acc[k] * inv + bias[cb + k], 0.f);
      o[k + 8] = fmaxf(acc[k + 8] * inv + bias[128 + cb + k], 0.f);
    }
    if (MODE == 1) {
      const u16x8 r0 = *reinterpret_cast<const u16x8*>(baseb + (size_t)n * DOUT + cb);
      const u16x8 r1 = *reinterpret_cast<const u16x8*>(baseb + (size_t)n * DOUT + 128 + cb);
      #pragma unroll
      for (int k = 0; k < 8; ++k) {
        o[k]     += b2f((unsigned short)r0[k]);
        o[k + 8] += b2f((unsigned short)r1[k]);
      }
    }
    if (OUT32) {
      *reinterpret_cast<float4*>(out + (size_t)n * DOUT + cb)           = make_float4(o[0], o[1], o[2], o[3]);
      *reinterpret_cast<float4*>(out + (size_t)n * DOUT + cb + 4)       = make_float4(o[4], o[5], o[6], o[7]);
      *reinterpret_cast<float4*>(out + (size_t)n * DOUT + 128 + cb)     = make_float4(o[8], o[9], o[10], o[11]);
      *reinterpret_cast<float4*>(out + (size_t)n * DOUT + 128 + cb + 4) = make_float4(o[12], o[13], o[14], o[15]);
    } else {
      u16x8 ob0, ob1;
      #pragma unroll
      for (int k = 0; k < 8; ++k) { ob0[k] = f2b(o[k]); ob1[k] = f2b(o[k + 8]); }
      *reinterpret_cast<u16x8*>(outb + (size_t)n * DOUT + cb)       = ob0;
      *reinterpret_cast<u16x8*>(outb + (size_t)n * DOUT + 128 + cb) = ob1;
    }
  }
}

// ---------------- launch ----------------
extern "C" void kernel_launch(void* const* d_in, const int* in_sizes, int n_in,
                              void* d_out, int out_size, void* d_ws, size_t ws_size,
                              hipStream_t stream) {
  const float* x   = (const float*)d_in[0];
  const int*   ei  = (const int*)d_in[1];
  const float* W1  = (const float*)d_in[2];
  const float* as1 = (const float*)d_in[3];
  const float* ad1 = (const float*)d_in[4];
  const float* b1  = (const float*)d_in[5];
  const float* W2  = (const float*)d_in[6];
  const float* as2 = (const float*)d_in[7];
  const float* ad2 = (const float*)d_in[8];
  const float* b2  = (const float*)d_in[9];
  const float* W3  = (const float*)d_in[10];
  const float* as3 = (const float*)d_in[11];
  const float* ad3 = (const float*)d_in[12];
  const float* b3  = (const float*)d_in[13];
  float* out = (float*)d_out;   // final fp32 output only

  char* ws = (char*)d_ws;
  size_t off = 0;
  auto alloc = [&](size_t bytes) -> void* {
    void* p = ws + off;
    off = (off + bytes + 255) & ~(size_t)255;
    return p;
  };
  unsigned short* Xb   = (unsigned short*)alloc((size_t)NNODES * 512 * sizeof(unsigned short));
  unsigned short* Hb   = (unsigned short*)alloc((size_t)NNODES * DOUT * sizeof(unsigned short));
  unsigned short* W1t  = (unsigned short*)alloc((size_t)512 * DOUT * sizeof(unsigned short));
  unsigned short* W2t  = (unsigned short*)alloc((size_t)DOUT * DOUT * sizeof(unsigned short));
  unsigned short* W3t  = (unsigned short*)alloc((size_t)DOUT * DOUT * sizeof(unsigned short));
  float* asn  = (float*)alloc(NNODES * sizeof(float));
  float* adn  = (float*)alloc(NNODES * sizeof(float));
  // deg + bcnt adjacent -> single memset
  int*   deg  = (int*)alloc(NNODES * sizeof(int) + NB * sizeof(int) + 256);
  int*   bcnt = deg + NNODES;
  int*   rowptr = (int*)alloc((NNODES + 1) * sizeof(int));
  int*   bsum = (int*)alloc(SCANB * sizeof(int));
  int*   esrc = (int*)alloc((size_t)(NEDGES + NNODES) * sizeof(int));
  int2*  bbuf = (int2*)alloc((size_t)NB * BCAP * sizeof(int2));

  hipMemsetAsync(deg, 0, (NNODES + NB) * sizeof(int), stream);

  // fat pre: bucket || castX || castW1-3
  const int preGrid = BBUCKET + BCASTX + 512 + 256 + 256;
  k_pre<<<preGrid, 256, 0, stream>>>(ei, deg, bcnt, bbuf,
                                     (const float4*)x, (ushort4*)Xb,
                                     W1, W1t, W2, W2t, W3, W3t);
  k_scan1<<<SCANB, 256, 0, stream>>>(deg, rowptr, bsum);
  k_scan23<<<SCANB, 256, 0, stream>>>(rowptr, bsum);

  // fat mid: unbucket || gemm layer 1
  k_mid<<<NB + GEMM_GRID, 256, 0, stream>>>(bbuf, bcnt, rowptr, esrc,
                                            Xb, W1t, as1, ad1, Hb, asn, adn);

  const int aggGrid = (NNODES + 3) / 4;

  // layer 1: Xb <- bf16 row (no fp32 mirror)
  k_agg<0, 0><<<aggGrid, 256, 0, stream>>>(Hb, rowptr, esrc, asn, adn, b1, nullptr, nullptr, Xb);
  // layer 2: in-place bf16 residual update of Xb
  k_gemm_mfma<256><<<GEMM_GRID, 256, 0, stream>>>(Xb, W2t, as2, ad2, Hb, asn, adn);
  k_agg<1, 0><<<aggGrid, 256, 0, stream>>>(Hb, rowptr, esrc, asn, adn, b2, Xb, nullptr, Xb);
  // layer 3: final fp32 output
  k_gemm_mfma<256><<<GEMM_GRID, 256, 0, stream>>>(Xb, W3t, as3, ad3, Hb, asn, adn);
  k_agg<1, 1><<<aggGrid, 256, 0, stream>>>(Hb, rowptr, esrc, asn, adn, b3, Xb, out, nullptr);
}